// Round 1
// 255.815 us; speedup vs baseline: 1.3201x; 1.3201x over previous
//
#include <hip/hip_runtime.h>

#define D 128
#define NROW 50000      // N_U == N_V == 50000
#define NEDGE 640000
#define CAP 64          // ELL row capacity; P(Poisson(12.8) >= 64) ~ 3e-23/row

// edge routing geometry
#define RBLK 160        // route blocks; 160*4000 == 640000
#define EPB  4000       // edges per route block
#define NBKT 196        // row buckets of 256 rows: ceil(50000/256)
#define CELL 64         // per-(bucket, route-block) record capacity
                        // mean 4000*256/50000 = 20.5, cap 64 => overflow ~2e-8 total

typedef __attribute__((ext_vector_type(8))) short short8;
typedef __attribute__((ext_vector_type(4))) float f32x4;

__device__ __forceinline__ unsigned short f2bf(float f) {
    unsigned u = __float_as_uint(f);
    unsigned r = (u + 0x7fff + ((u >> 16) & 1)) >> 16;  // round-nearest-even
    return (unsigned short)r;
}
// accumulate packed bf16 pair (lo->e, hi->o)
__device__ __forceinline__ void acc2(float& e, float& o, unsigned g) {
    e += __uint_as_float(g << 16);
    o += __uint_as_float(g & 0xffff0000u);
}

// ============================================================
// K1 route_gemm1: bucket edges by row>>8 into per-(bucket,block)
// segments via LDS atomics; coalesced 256B segment writes.
// No global atomics anywhere. + small_gemm1 (T = [W0;b0;b1] @ W1).
// record = (key16 << 16) | payload16  (both < 50000 < 65536)
// counts layout: block-major counts[blk*NBKT + k] (coalesced write)
// ============================================================
__global__ __launch_bounds__(256) void route_gemm1(const int* __restrict__ eu,
                                                   const int* __restrict__ ev,
                                                   unsigned int* __restrict__ recbuf_u,
                                                   int* __restrict__ counts_u,
                                                   unsigned int* __restrict__ recbuf_v,
                                                   int* __restrict__ counts_v,
                                                   const float* __restrict__ W0,
                                                   const float* __restrict__ b0,
                                                   const float* __restrict__ b1,
                                                   const float* __restrict__ W1,
                                                   float* __restrict__ T) {
    const int blk = blockIdx.x, tid = threadIdx.x;
    if (blk < RBLK) {
        __shared__ int cnt_s[NBKT];
        __shared__ unsigned int rec_s[NBKT * CELL];   // 49 KB
        const int base = blk * EPB;
        for (int dir = 0; dir < 2; dir++) {
            const int* __restrict__ kk = dir ? ev : eu;   // key (destination row)
            const int* __restrict__ pp = dir ? eu : ev;   // payload (source row)
            unsigned int* __restrict__ recbuf = dir ? recbuf_v : recbuf_u;
            int* __restrict__ counts = dir ? counts_v : counts_u;
            if (tid < NBKT) cnt_s[tid] = 0;
            __syncthreads();
            for (int e0 = tid; e0 < EPB; e0 += 256) {
                int e = base + e0;
                int key = kk[e], pay = pp[e];
                int k = key >> 8;
                int p = atomicAdd(&cnt_s[k], 1);          // LDS atomic
                if (p < CELL) rec_s[k * CELL + p] = ((unsigned)key << 16) | (unsigned)pay;
            }
            __syncthreads();
            if (tid < NBKT) {
                int c = cnt_s[tid];
                counts[blk * NBKT + tid] = (c < CELL) ? c : CELL;
            }
            const int wave = tid >> 6, lane = tid & 63;
            for (int k = wave; k < NBKT; k += 4) {        // 49 segments/wave
                int c = cnt_s[k]; c = (c < CELL) ? c : CELL;
                if (lane < c)
                    recbuf[(size_t)(k * RBLK + blk) * CELL + lane] = rec_s[k * CELL + lane];
            }
            __syncthreads();
        }
    } else {                          // small_gemm1: T (130x128) = [W0; b0; b1] @ W1
        __shared__ float R[2][128];
        int idx = blk - RBLK;
        int sub = tid >> 7, j = tid & 127;
        int i = idx * 2 + sub;
        bool valid = (i < 130);
        const float* row = nullptr;
        if (valid && i < 128) row = W0 + i * D;
        else if (valid && i == 128) row = b0;
        R[sub][j] = row ? row[j] : 0.f;
        __syncthreads();
        if (!valid) return;
        if (i == 129) { T[129 * D + j] = b1[j]; return; }
        float acc = 0.f;
#pragma unroll 8
        for (int k = 0; k < 128; k++) acc += R[sub][k] * W1[k * D + j];
        T[i * D + j] = acc;
    }
}

// ============================================================
// K2: ELL build (blocks [0,392)) + cvt_bf16 ([392,6642)) + sg2 ([6642,6707))
// ELL build: one block per (direction, bucket). Builds the 256-row x CAP
// ELL tile in LDS (LDS cursor atomics), then writes tile + exact degrees
// fully coalesced. Replaces 1.28M device-scope atomics + random 2B stores.
// ============================================================
__global__ __launch_bounds__(256) void ellbuild_cvt_sg2(const unsigned int* __restrict__ recbuf_u,
                                                        const int* __restrict__ counts_u,
                                                        const unsigned int* __restrict__ recbuf_v,
                                                        const int* __restrict__ counts_v,
                                                        unsigned short* __restrict__ ell_u,
                                                        int* __restrict__ cnt_u,
                                                        unsigned short* __restrict__ ell_v,
                                                        int* __restrict__ cnt_v,
                                                        const float4* __restrict__ Xv4,
                                                        ushort4* __restrict__ Xb4,
                                                        const float* __restrict__ T,
                                                        const float* __restrict__ W2,
                                                        float* __restrict__ P,
                                                        unsigned short* __restrict__ PbT) {
    const int blk = blockIdx.x, tid = threadIdx.x;
    if (blk < 2 * NBKT) {
        const int dir = (blk >= NBKT) ? 1 : 0;
        const int k = dir ? blk - NBKT : blk;
        const unsigned int* __restrict__ recbuf = dir ? recbuf_v : recbuf_u;
        const int* __restrict__ counts = dir ? counts_v : counts_u;
        unsigned short* __restrict__ ell = dir ? ell_v : ell_u;
        int* __restrict__ cnt = dir ? cnt_v : cnt_u;

        __shared__ __align__(16) unsigned short ell_s[256 * CAP];  // 32 KB
        __shared__ int cnt_s[256];
        __shared__ int seg_c[RBLK];
        cnt_s[tid] = 0;
        if (tid < RBLK) seg_c[tid] = counts[tid * NBKT + k];
        __syncthreads();

        const int wave = tid >> 6, lane = tid & 63;
        const unsigned int* rb = recbuf + (size_t)k * RBLK * CELL;
        // 2-stage software pipeline over this wave's segments (b = wave, wave+4, ...)
        int b = wave;
        int c0 = seg_c[b];
        unsigned int r0 = 0;
        if (lane < c0) r0 = rb[b * CELL + lane];
        while (b < RBLK) {
            int bn = b + 4;
            int c1 = 0; unsigned int r1 = 0;
            if (bn < RBLK) { c1 = seg_c[bn]; if (lane < c1) r1 = rb[bn * CELL + lane]; }
            if (lane < c0) {
                int lr = (r0 >> 16) & 255;                 // row within bucket
                int p = atomicAdd(&cnt_s[lr], 1);          // LDS atomic (exact degree)
                if (p < CAP) ell_s[lr * CAP + p] = (unsigned short)(r0 & 0xffff);
            }
            b = bn; c0 = c1; r0 = r1;
        }
        __syncthreads();
        const int row0 = k << 8;
        const int nrows = (row0 + 256 <= NROW) ? 256 : (NROW - row0);  // bucket 195: 80
        const uint4* src = (const uint4*)ell_s;
        uint4* dst = (uint4*)(ell + (size_t)row0 * CAP);
        for (int i = tid; i < nrows * 8; i += 256) dst[i] = src[i];    // coalesced 128B rows
        if (tid < nrows) cnt[row0 + tid] = cnt_s[tid];
    } else if (blk < 2 * NBKT + 6250) {   // cvt: n4 = 1,600,000 = 6250*256 exactly
        int i = (blk - 2 * NBKT) * 256 + tid;
        float4 v = Xv4[i];
        ushort4 o;
        o.x = f2bf(v.x); o.y = f2bf(v.y); o.z = f2bf(v.z); o.w = f2bf(v.w);
        Xb4[i] = o;
    } else {                              // small_gemm2: P = T @ W2, PbT = bf16(P^T)
        __shared__ float R[2][128];
        int idx = blk - (2 * NBKT + 6250);
        int sub = tid >> 7, j = tid & 127;
        int i = idx * 2 + sub;
        bool valid = (i < 130);
        R[sub][j] = valid ? T[i * D + j] : 0.f;
        __syncthreads();
        if (!valid) return;
        float acc = 0.f;
#pragma unroll 8
        for (int kk = 0; kk < 128; kk++) acc += R[sub][kk] * W2[kk * D + j];
        P[i * D + j] = acc;
        if (i < 128) PbT[j * 128 + i] = f2bf(acc);
    }
}

// ============================================================
// gather (subwave-16): OUTb[r] = bf16( sum_{s in ELL[r]} A[s] )
// ============================================================
__device__ __forceinline__ void gather_body(const unsigned short* __restrict__ A,
                                            const int* __restrict__ cnt,
                                            const unsigned short* __restrict__ ell,
                                            unsigned short* __restrict__ OUTb,
                                            int blk) {
    int r = blk * 16 + (threadIdx.x >> 4);          // 50000 % 16 == 0
    int c = threadIdx.x & 15;                        // 16B chunk within row
    int n = cnt[r]; n = (n < CAP) ? n : CAP;
    const unsigned short* idx = ell + (size_t)r * CAP;
    float a0 = 0.f, a1 = 0.f, a2 = 0.f, a3 = 0.f, a4 = 0.f, a5 = 0.f, a6 = 0.f, a7 = 0.f;
    int i = 0;
    for (; i + 4 <= n; i += 4) {
        int s0 = idx[i], s1 = idx[i + 1], s2 = idx[i + 2], s3 = idx[i + 3];
        uint4 q0 = *(const uint4*)(A + (size_t)s0 * D + c * 8);
        uint4 q1 = *(const uint4*)(A + (size_t)s1 * D + c * 8);
        uint4 q2 = *(const uint4*)(A + (size_t)s2 * D + c * 8);
        uint4 q3 = *(const uint4*)(A + (size_t)s3 * D + c * 8);
        acc2(a0, a1, q0.x); acc2(a2, a3, q0.y); acc2(a4, a5, q0.z); acc2(a6, a7, q0.w);
        acc2(a0, a1, q1.x); acc2(a2, a3, q1.y); acc2(a4, a5, q1.z); acc2(a6, a7, q1.w);
        acc2(a0, a1, q2.x); acc2(a2, a3, q2.y); acc2(a4, a5, q2.z); acc2(a6, a7, q2.w);
        acc2(a0, a1, q3.x); acc2(a2, a3, q3.y); acc2(a4, a5, q3.z); acc2(a6, a7, q3.w);
    }
    for (; i < n; i++) {
        uint4 q0 = *(const uint4*)(A + (size_t)idx[i] * D + c * 8);
        acc2(a0, a1, q0.x); acc2(a2, a3, q0.y); acc2(a4, a5, q0.z); acc2(a6, a7, q0.w);
    }
    uint4 o;
    o.x = (unsigned)f2bf(a0) | ((unsigned)f2bf(a1) << 16);
    o.y = (unsigned)f2bf(a2) | ((unsigned)f2bf(a3) << 16);
    o.z = (unsigned)f2bf(a4) | ((unsigned)f2bf(a5) << 16);
    o.w = (unsigned)f2bf(a6) | ((unsigned)f2bf(a7) << 16);
    *(uint4*)(OUTb + (size_t)r * D + c * 8) = o;
}

// K3: hop 1 (v2u) + t_k (t[v] = sum cnt_u over ell_v row — needs K2's cnt/ell)
__global__ __launch_bounds__(256) void gather1_tk(const unsigned short* __restrict__ A,
                                                  const int* __restrict__ cnt_u,
                                                  const unsigned short* __restrict__ ell_u,
                                                  unsigned short* __restrict__ OUTb,
                                                  const int* __restrict__ cnt_v,
                                                  const unsigned short* __restrict__ ell_v,
                                                  int* __restrict__ t) {
    if (blockIdx.x < 3125) {
        gather_body(A, cnt_u, ell_u, OUTb, blockIdx.x);
    } else {
        int v = (blockIdx.x - 3125) * 256 + threadIdx.x;
        if (v >= NROW) return;
        int n = cnt_v[v]; n = (n < CAP) ? n : CAP;
        const unsigned short* row = ell_v + (size_t)v * CAP;
        int s = 0;
        for (int i = 0; i < n; i++) s += cnt_u[row[i]];
        t[v] = s;
    }
}

// K4: hop 2 (u2v) + g23 (g2[u]=sum t[s], g3[u]=sum cnt_v[s] over ell_u row)
__global__ __launch_bounds__(256) void gather2_g23(const unsigned short* __restrict__ A,
                                                   const int* __restrict__ cnt_v,
                                                   const unsigned short* __restrict__ ell_v,
                                                   unsigned short* __restrict__ OUTb,
                                                   const int* __restrict__ cnt_u,
                                                   const unsigned short* __restrict__ ell_u,
                                                   const int* __restrict__ t,
                                                   int* __restrict__ g2, int* __restrict__ g3) {
    if (blockIdx.x < 3125) {
        gather_body(A, cnt_v, ell_v, OUTb, blockIdx.x);
    } else {
        int u = (blockIdx.x - 3125) * 256 + threadIdx.x;
        if (u >= NROW) return;
        int n = cnt_u[u]; n = (n < CAP) ? n : CAP;
        const unsigned short* row = ell_u + (size_t)u * CAP;
        int a = 0, b = 0;
        for (int i = 0; i < n; i++) {
            int s = row[i];
            a += t[s];
            b += cnt_v[s];
        }
        g2[u] = a;
        g3[u] = b;
    }
}

// K5: hop 3 (v2u)
__global__ __launch_bounds__(256) void gather_rows(const unsigned short* __restrict__ A,
                                                   const int* __restrict__ cnt,
                                                   const unsigned short* __restrict__ ell,
                                                   unsigned short* __restrict__ OUTb) {
    gather_body(A, cnt, ell, OUTb, blockIdx.x);
}

// ============================================================
// K6: MFMA final GEMM + rank-3 fp32 bias epilogue.
// OUT[r][j] = (Z @ W0W1W2)[r][j] + g2[r]*c0[j] + g3[r]*c1[j] + du[r]*b2[j]
// ============================================================
__global__ __launch_bounds__(256) void gemm_final_mfma(const unsigned short* __restrict__ Z,
                                                       const unsigned short* __restrict__ PbT,
                                                       const float* __restrict__ P,
                                                       const float* __restrict__ b2,
                                                       const int* __restrict__ g2,
                                                       const int* __restrict__ g3,
                                                       const int* __restrict__ du,
                                                       float* __restrict__ OUT) {
    const int wave = threadIdx.x >> 6;
    const int lane = threadIdx.x & 63;
    const int ml = lane & 15;      // m (A-row / D-col) index
    const int quad = lane >> 4;    // k-quad / D-row-quad
    const int m0 = blockIdx.x * 64 + wave * 16;
    if (m0 >= NROW) return;        // 50000 = 781*64 + 16: block 781 waves 1..3 idle

    const uint4* zr = (const uint4*)(Z + (size_t)(m0 + ml) * D);

    f32x4 acc[8];
#pragma unroll
    for (int nt = 0; nt < 8; nt++) acc[nt] = (f32x4){0.f, 0.f, 0.f, 0.f};

#pragma unroll
    for (int kc = 0; kc < 4; kc++) {
        short8 a = __builtin_bit_cast(short8, zr[kc * 4 + quad]);
#pragma unroll
        for (int nt = 0; nt < 8; nt++) {
            const uint4* br = (const uint4*)(PbT + (size_t)(nt * 16 + ml) * D);
            short8 b = __builtin_bit_cast(short8, br[kc * 4 + quad]);
            acc[nt] = __builtin_amdgcn_mfma_f32_16x16x32_bf16(a, b, acc[nt], 0, 0, 0);
        }
    }

    float sg2[4], sg3[4], sdu[4];
#pragma unroll
    for (int reg = 0; reg < 4; reg++) {
        int r = m0 + quad * 4 + reg;
        sg2[reg] = (float)g2[r];
        sg3[reg] = (float)g3[r];
        sdu[reg] = (float)du[r];
    }
    const float* c0 = P + 128 * D;
    const float* c1 = P + 129 * D;
#pragma unroll
    for (int nt = 0; nt < 8; nt++) {
        int col = nt * 16 + ml;
        float cc0 = c0[col], cc1 = c1[col], cb2 = b2[col];
#pragma unroll
        for (int reg = 0; reg < 4; reg++) {
            int r = m0 + quad * 4 + reg;
            OUT[(size_t)r * D + col] = acc[nt][reg] + sg2[reg] * cc0 + sg3[reg] * cc1 + sdu[reg] * cb2;
        }
    }
}

// ============================================================
extern "C" void kernel_launch(void* const* d_in, const int* in_sizes, int n_in,
                              void* d_out, int out_size, void* d_ws, size_t ws_size,
                              hipStream_t stream) {
    // 0=X_u(unused), 1=X_v, 2=edge_u, 3=edge_v, 4=W0, 5=b0, 6=W1, 7=b1, 8=W2, 9=b2
    const float* X_v = (const float*)d_in[1];
    const int* edge_u = (const int*)d_in[2];
    const int* edge_v = (const int*)d_in[3];
    const float* W0 = (const float*)d_in[4];
    const float* b0 = (const float*)d_in[5];
    const float* W1 = (const float*)d_in[6];
    const float* b1 = (const float*)d_in[7];
    const float* W2 = (const float*)d_in[8];
    const float* b2 = (const float*)d_in[9];

    // ---- ws layout (~43.1 MB; >= 51.2 MB proven) ----
    char* w = (char*)d_ws;
    unsigned short* A = (unsigned short*)w;                    // bf16 [NROW x 128] = 12.8 MB
    unsigned short* ell_u = (unsigned short*)(w + 12800000);   // NROW*CAP ushort = 6.4 MB
    unsigned short* ell_v = ell_u + (size_t)NROW * CAP;        // 6.4 MB
    int* cnt_u = (int*)(ell_v + (size_t)NROW * CAP);           // 50000 (exact degrees)
    int* cnt_v = cnt_u + NROW;                                 // 50000
    int* tbuf  = cnt_v + NROW;                                 // 50000
    int* g2    = tbuf + NROW;                                  // 50000
    int* g3    = g2 + NROW;                                    // 50000
    float* T   = (float*)(g3 + NROW);                          // 130*128
    float* P   = T + 130 * D;                                  // 130*128
    unsigned short* PbT = (unsigned short*)(P + 130 * D);      // 128*128 bf16
    unsigned int* recbuf_u = (unsigned int*)(PbT + 128 * 128); // 196*160*64 u32 = 8.03 MB
    unsigned int* recbuf_v = recbuf_u + (size_t)NBKT * RBLK * CELL;  // 8.03 MB
    int* counts_u = (int*)(recbuf_v + (size_t)NBKT * RBLK * CELL);   // 196*160 = 125 KB
    int* counts_v = counts_u + NBKT * RBLK;                          // 125 KB

    float* OUT = (float*)d_out;
    unsigned short* B = (unsigned short*)d_out;                // bf16 ping buffer (dead before final GEMM)

    const dim3 blk(256);

    // K1: edge routing (160) + small_gemm1 (65). No memset needed anymore.
    route_gemm1<<<RBLK + 65, blk, 0, stream>>>(edge_u, edge_v,
                                               recbuf_u, counts_u, recbuf_v, counts_v,
                                               W0, b0, b1, W1, T);
    // K2: ELL build in LDS (392) + cvt (6250) + small_gemm2 (65)
    ellbuild_cvt_sg2<<<2 * NBKT + 6250 + 65, blk, 0, stream>>>(recbuf_u, counts_u,
                                                               recbuf_v, counts_v,
                                                               ell_u, cnt_u, ell_v, cnt_v,
                                                               (const float4*)X_v, (ushort4*)B,
                                                               T, W2, P, PbT);
    // K3: hop 1 (v2u) + t_k
    gather1_tk<<<3125 + 196, blk, 0, stream>>>(B, cnt_u, ell_u, A, cnt_v, ell_v, tbuf);
    // K4: hop 2 (u2v) + g23
    gather2_g23<<<3125 + 196, blk, 0, stream>>>(A, cnt_v, ell_v, B, cnt_u, ell_u, tbuf, g2, g3);
    // K5: hop 3 (v2u)
    gather_rows<<<3125, blk, 0, stream>>>(B, cnt_u, ell_u, A);
    // K6: final MFMA GEMM + exact rank-3 bias epilogue
    gemm_final_mfma<<<782, blk, 0, stream>>>(A, PbT, P, b2, g2, g3, cnt_u, OUT);
}